// Round 11
// baseline (576.673 us; speedup 1.0000x reference)
//
#include <hip/hip_runtime.h>

#define HIDDEN 64
#define CF 8         // features per chunk (32 B row = 2 float4)
#define NCHUNK 8     // chunks; chunk = blockIdx&7 -> XCD round-robin, 3.2 MB < 4 MB L2
#define RANGE 8192   // nodes per histogram range
#define RSHIFT 13
#define PPART 64     // edge partitions
#define PSHIFT 6

// ---------- atomic-free degree histograms (packed u16 pairs) ----------
__global__ __launch_bounds__(256) void hist_kernel(const int* __restrict__ src,
                                                   const int* __restrict__ dst,
                                                   int* __restrict__ inpart,
                                                   int* __restrict__ outpart,
                                                   int E, int Ep, int Npad2) {
    __shared__ int hin[RANGE / 2];
    __shared__ int hout[RANGE / 2];
    int r = blockIdx.x >> PSHIFT, p = blockIdx.x & (PPART - 1);
    int base = r << RSHIFT;
    for (int i = threadIdx.x; i < RANGE / 2; i += 256) { hin[i] = 0; hout[i] = 0; }
    __syncthreads();
    int es = p * Ep, ee = min(E, es + Ep);
    for (int e = es + threadIdx.x; e < ee; e += 256) {
        int d = dst[e], s = src[e];
        unsigned dd = (unsigned)(d - base), ss = (unsigned)(s - base);
        if (dd < RANGE) atomicAdd(&hin[dd >> 1], 1 << ((dd & 1) << 4));
        if (ss < RANGE) atomicAdd(&hout[ss >> 1], 1 << ((ss & 1) << 4));
    }
    __syncthreads();
    int* ip = inpart + (size_t)p * Npad2 + (base >> 1);
    int* op = outpart + (size_t)p * Npad2 + (base >> 1);
    for (int i = threadIdx.x; i < RANGE / 2; i += 256) { ip[i] = hin[i]; op[i] = hout[i]; }
}

// ---------- per-node-pair: totals, exclusive prefix over partitions, norms,
// padded-degree block sums ----------
__global__ __launch_bounds__(256) void prefix_kernel(int* __restrict__ inpart,
                                                     const int* __restrict__ outpart,
                                                     int* __restrict__ indeg,
                                                     float* __restrict__ nsrc,
                                                     float* __restrict__ ndst,
                                                     int* __restrict__ bsum,
                                                     int N, int Npad2) {
    int t = threadIdx.x;
    int w = blockIdx.x * 256 + t;     // word index = node pair
    int n0 = w << 1;
    int run0 = 0, run1 = 0, od0 = 0, od1 = 0;
    if (n0 < N) {
#pragma unroll 4
        for (int p = 0; p < PPART; p++) {
            size_t idx = (size_t)p * Npad2 + w;
            int c = inpart[idx];
            int o = outpart[idx];
            inpart[idx] = (run0 & 0xffff) | (run1 << 16);
            run0 += c & 0xffff;  run1 += (c >> 16) & 0xffff;
            od0  += o & 0xffff;  od1  += (o >> 16) & 0xffff;
        }
        indeg[n0] = run0;
        nsrc[n0] = rsqrtf(fmaxf((float)od0, 1.0f));
        ndst[n0] = rsqrtf(fmaxf((float)run0, 1.0f));
        if (n0 + 1 < N) {
            indeg[n0 + 1] = run1;
            nsrc[n0 + 1] = rsqrtf(fmaxf((float)od1, 1.0f));
            ndst[n0 + 1] = rsqrtf(fmaxf((float)run1, 1.0f));
        }
    }
    int v = ((run0 + 15) & ~15) + ((run1 + 15) & ~15);
#pragma unroll
    for (int off = 32; off > 0; off >>= 1) v += __shfl_down(v, off, 64);
    __shared__ int s[4];
    if ((t & 63) == 0) s[t >> 6] = v;
    __syncthreads();
    if (t == 0) {
        bsum[2 * blockIdx.x]     = s[0] + s[1];
        bsum[2 * blockIdx.x + 1] = s[2] + s[3];
    }
}

__global__ void scan_bsum_kernel(int* __restrict__ bsum, int B) {
    __shared__ int tmp[1024];
    int t = threadIdx.x;
    tmp[t] = (t < B) ? bsum[t] : 0;
    __syncthreads();
    for (int off = 1; off < 1024; off <<= 1) {
        int u = (t >= off) ? tmp[t - off] : 0;
        __syncthreads();
        tmp[t] += u;
        __syncthreads();
    }
    if (t < B) bsum[t] = (t > 0) ? tmp[t - 1] : 0;
}

// padded inclusive scan -> row_ptr, fused sentinel pad-fill
__global__ void scan_final_kernel(const int* __restrict__ indeg, const int* __restrict__ bsum,
                                  int* __restrict__ row_ptr, int* __restrict__ col, int N) {
    __shared__ int tmp[256];
    int t = threadIdx.x;
    int n = blockIdx.x * 256 + t;
    int id = (n < N) ? indeg[n] : 0;
    int v = (id + 15) & ~15;
    tmp[t] = (n < N) ? v : 0;
    __syncthreads();
    for (int off = 1; off < 256; off <<= 1) {
        int u = (t >= off) ? tmp[t - off] : 0;
        __syncthreads();
        tmp[t] += u;
        __syncthreads();
    }
    if (n < N) {
        int rp1 = tmp[t] + bsum[blockIdx.x];
        row_ptr[n + 1] = rp1;
        for (int j = rp1 - v + id; j < rp1; j++) col[j] = N;
    }
    if (n == 0) row_ptr[0] = 0;
}

// ---------- atomic-free CSR fill: packed LDS cursors per (range,partition) ----------
__global__ __launch_bounds__(256) void fill_kernel(const int* __restrict__ src,
                                                   const int* __restrict__ dst,
                                                   const int* __restrict__ inpart,
                                                   const int* __restrict__ row_ptr,
                                                   int* __restrict__ col,
                                                   int E, int Ep, int Npad2) {
    __shared__ int lcur[RANGE / 2];
    int r = blockIdx.x >> PSHIFT, p = blockIdx.x & (PPART - 1);
    int base = r << RSHIFT;
    for (int i = threadIdx.x; i < RANGE / 2; i += 256) lcur[i] = 0;
    __syncthreads();
    const int* offs = inpart + (size_t)p * Npad2;
    int es = p * Ep, ee = min(E, es + Ep);
    for (int e = es + threadIdx.x; e < ee; e += 256) {
        int d = dst[e];
        unsigned dd = (unsigned)(d - base);
        if (dd < RANGE) {
            int sh = (dd & 1) << 4;
            int old = atomicAdd(&lcur[dd >> 1], 1 << sh);
            int lrank = (old >> sh) & 0xffff;
            int pbase = (offs[d >> 1] >> ((d & 1) << 4)) & 0xffff;
            col[row_ptr[d] + pbase + lrank] = src[e];
        }
    }
}

// ---------- embW = emb @ W0 ----------
__global__ __launch_bounds__(256) void embw_kernel(const float* __restrict__ emb,
                                                   const float* __restrict__ W,
                                                   float* __restrict__ embW, int V) {
    __shared__ float Wsh[HIDDEN * HIDDEN];
    for (int i = threadIdx.x; i < HIDDEN * HIDDEN; i += blockDim.x) Wsh[i] = W[i];
    __syncthreads();
    int lane = threadIdx.x & 63;
    int v = blockIdx.x * 4 + (threadIdx.x >> 6);
    if (v >= V) return;
    float rv = emb[(size_t)v * HIDDEN + lane];
    float o = 0.0f;
#pragma unroll
    for (int k = 0; k < HIDDEN; k++) o = fmaf(__shfl(rv, k, 64), Wsh[k * HIDDEN + lane], o);
    embW[(size_t)v * HIDDEN + lane] = o;
}

// ---------- w~ = W2 @ Wreg ; wt[64] = b2 . Wreg ; q[N] = 0 ----------
__global__ void wtilde_kernel(const float* __restrict__ W2, const float* __restrict__ Wreg,
                              const float* __restrict__ b2, float* __restrict__ wt,
                              float* __restrict__ q, int N) {
    int k = threadIdx.x;
    float s = 0.0f;
    for (int j = 0; j < HIDDEN; j++) s += W2[k * HIDDEN + j] * Wreg[j];
    wt[k] = s;
    float cv = b2[k] * Wreg[k];
#pragma unroll
    for (int off = 32; off > 0; off >>= 1) cv += __shfl_down(cv, off, 64);
    if (k == 0) { wt[HIDDEN] = cv; q[N] = 0.0f; }
}

// ---------- gather1 (+ sentinel row zeroing): over N1 rows ----------
__global__ void gather1_kernel(const int* __restrict__ feats, const float* __restrict__ embW,
                               const float* __restrict__ nsrc, float* __restrict__ hT,
                               int N, int N1, int total) {
    int idx = blockIdx.x * blockDim.x + threadIdx.x;   // c*(N1*8) + n*8 + f
    if (idx >= total) return;
    int c = idx / (N1 * CF);
    int r = idx - c * (N1 * CF);
    int n = r >> 3;
    int f = r & 7;
    hT[idx] = (n < N) ? embW[feats[n] * HIDDEN + c * CF + f] * nsrc[n] : 0.0f;
}

// ---------- dense 64x64 layer, chunked CF8 in/out, 2-node ILP ----------
__global__ __launch_bounds__(256) void dense_kernel(const float* __restrict__ inT,
                                                    const float* __restrict__ W,
                                                    float* __restrict__ outT,
                                                    int N, int N1, int nstride) {
    __shared__ float Wsh[HIDDEN * HIDDEN];
    for (int i = threadIdx.x; i < HIDDEN * HIDDEN; i += blockDim.x) Wsh[i] = W[i];
    __syncthreads();

    int lane = threadIdx.x & 63;
    int warp = threadIdx.x >> 6;
    size_t rowoff = (size_t)(lane >> 3) * N1;
    int f = lane & 7;

    for (int n0 = blockIdx.x * 4 + warp; n0 < N; n0 += 2 * nstride) {
        int n1 = n0 + nstride;
        float rv0 = inT[(rowoff + n0) * CF + f];
        float rv1 = (n1 < N) ? inT[(rowoff + n1) * CF + f] : 0.0f;
        float o0 = 0.0f, o1 = 0.0f;
#pragma unroll
        for (int k = 0; k < HIDDEN; k++) {
            float w = Wsh[k * HIDDEN + lane];
            o0 = fmaf(__shfl(rv0, k, 64), w, o0);
            o1 = fmaf(__shfl(rv1, k, 64), w, o1);
        }
        outT[(rowoff + n0) * CF + f] = o0;
        if (n1 < N) outT[(rowoff + n1) * CF + f] = o1;
    }
}

// ---------- chunked gather-SpMM: CF8 L2-resident, padded CSR, float4,
// 4 independent chains x 2 lane-halves = 8 nodes per wave-iteration ----------
// lane = nh*32 + e*2 + fq: nh = half (node group select), e = 16 edge slots,
// fq = which float4 of the 32B row. Rows padded to x16 with sentinel N (zero
// row), so the inner loop needs no per-lane predication: chain k runs m[k]
// iterations (uniform within each half; exec-mask handles cross-half skew).
__global__ __launch_bounds__(256) void spmm_kernel(const int* __restrict__ row_ptr,
                                                   const int* __restrict__ col,
                                                   const float* __restrict__ tmpT,
                                                   const float* __restrict__ ndst,
                                                   const float* __restrict__ nsrc,
                                                   const float* __restrict__ b,
                                                   float* __restrict__ outT,
                                                   int N, int N1, int nstride) {
    int lane = threadIdx.x & 63;
    int warp = threadIdx.x >> 6;
    int c = blockIdx.x & 7;
    int nh = lane >> 5;
    int e  = (lane >> 1) & 15;
    int fq = lane & 1;
    const float* __restrict__ chunk = tmpT + (size_t)c * N1 * CF;
    float4 bias = ((const float4*)(b + c * CF))[fq];

    int start = (blockIdx.x >> 3) * 4 + warp;
    for (int n0 = start; n0 < N; n0 += 8 * nstride) {
        int nk[4], j[4], m[4];
        float4 acc[4];
        int mmax = 0;
#pragma unroll
        for (int k = 0; k < 4; k++) {
            nk[k] = n0 + (2 * k + nh) * nstride;
            int beg = 0, end = 0;
            if (nk[k] < N) { beg = row_ptr[nk[k]]; end = row_ptr[nk[k] + 1]; }
            j[k] = beg + e;
            m[k] = (end - beg) >> 4;
            mmax = max(mmax, m[k]);
            acc[k] = make_float4(0.f, 0.f, 0.f, 0.f);
        }
        for (int it = 0; it < mmax; it++) {
#pragma unroll
            for (int k = 0; k < 4; k++) {
                if (it < m[k]) {
                    int s = col[j[k]];
                    float4 v = *(const float4*)(chunk + (size_t)s * CF + fq * 4);
                    acc[k].x += v.x; acc[k].y += v.y; acc[k].z += v.z; acc[k].w += v.w;
                    j[k] += 16;
                }
            }
        }
#pragma unroll
        for (int k = 0; k < 4; k++) {
#pragma unroll
            for (int mm = 2; mm <= 16; mm <<= 1) {
                acc[k].x += __shfl_xor(acc[k].x, mm, 64);
                acc[k].y += __shfl_xor(acc[k].y, mm, 64);
                acc[k].z += __shfl_xor(acc[k].z, mm, 64);
                acc[k].w += __shfl_xor(acc[k].w, mm, 64);
            }
            if (e == 0 && nk[k] < N) {   // lanes 0,1,32,33
                float nd = ndst[nk[k]], ns = nsrc[nk[k]];
                float4 o;
                o.x = (acc[k].x * nd + bias.x) * ns;
                o.y = (acc[k].y * nd + bias.y) * ns;
                o.z = (acc[k].z * nd + bias.z) * ns;
                o.w = (acc[k].w * nd + bias.w) * ns;
                *(float4*)(outT + ((size_t)c * N1 + nk[k]) * CF + fq * 4) = o;
            }
        }
    }
}

// ---------- q[n] = hT[n] . w~ (8 chunks of 8) ----------
__global__ __launch_bounds__(256) void qdot_kernel(const float* __restrict__ hT,
                                                   const float* __restrict__ wt,
                                                   float* __restrict__ q, int N, int N1) {
    int lane = threadIdx.x & 63;
    int warp = threadIdx.x >> 6;
    int ns_ = lane >> 3, f = lane & 7;
    int n = (blockIdx.x * 4 + warp) * 8 + ns_;
    float acc = 0.0f;
#pragma unroll
    for (int c = 0; c < NCHUNK; c++) {
        float v = (n < N) ? hT[((size_t)c * N1 + n) * CF + f] : 0.0f;
        acc += v * wt[c * CF + f];
    }
    acc += __shfl_xor(acc, 1, 64);
    acc += __shfl_xor(acc, 2, 64);
    acc += __shfl_xor(acc, 4, 64);
    if (f == 0 && n < N) q[n] = acc;
}

// ---------- layer-3 scalar gather (padded CSR, 16 lanes/node) ----------
__global__ __launch_bounds__(256) void spmm3_kernel(const int* __restrict__ row_ptr,
                                                    const int* __restrict__ col,
                                                    const float* __restrict__ q,
                                                    const float* __restrict__ ndst,
                                                    float* __restrict__ nodeval, int N) {
    int lane = threadIdx.x & 63;
    int warp = threadIdx.x >> 6;
    int ns_ = lane >> 4, ln = lane & 15;
    int n = blockIdx.x * 16 + warp * 4 + ns_;
    if (n >= N) return;
    int beg = row_ptr[n], end = row_ptr[n + 1];
    float acc = 0.0f;
    for (int j = beg + ln; j < end; j += 16) acc += q[col[j]];
    acc += __shfl_xor(acc, 1, 64);
    acc += __shfl_xor(acc, 2, 64);
    acc += __shfl_xor(acc, 4, 64);
    acc += __shfl_xor(acc, 8, 64);
    if (ln == 0) nodeval[n] = acc * ndst[n];
}

// ---------- final: segmented sum over sorted gids ----------
__global__ __launch_bounds__(256) void final_kernel(const int* __restrict__ gids,
                                                    const float* __restrict__ nodeval,
                                                    const float* __restrict__ wt,
                                                    float* __restrict__ out, int N) {
    int n = blockIdx.x * 256 + threadIdx.x;
    int lane = threadIdx.x & 63;
    float c3 = wt[HIDDEN];
    float v = 0.0f;
    int g = -1;
    if (n < N) { v = nodeval[n] + c3; g = gids[n]; }
#pragma unroll
    for (int off = 1; off < 64; off <<= 1) {
        float u = __shfl_up(v, off, 64);
        int gu = __shfl_up(g, off, 64);
        if (lane >= off && gu == g) v += u;
    }
    int gn = __shfl_down(g, 1, 64);
    bool last = (lane == 63) || (gn != g);
    if (n < N && last) atomicAdd(&out[g], v);
}

extern "C" void kernel_launch(void* const* d_in, const int* in_sizes, int n_in,
                              void* d_out, int out_size, void* d_ws, size_t ws_size,
                              hipStream_t stream) {
    const int*   feats = (const int*)d_in[0];
    const int*   src   = (const int*)d_in[1];
    const int*   dst   = (const int*)d_in[2];
    const int*   gids  = (const int*)d_in[3];
    const float* emb   = (const float*)d_in[5];
    const float* Ws    = (const float*)d_in[6];
    const float* bs    = (const float*)d_in[7];
    const float* Wreg  = (const float*)d_in[8];
    float* out = (float*)d_out;

    int N = in_sizes[0];
    int E = in_sizes[1];
    int V = in_sizes[5] / HIDDEN;
    int N1 = N + 1;                 // +1 sentinel row per chunk
    int NB = (N + 255) / 256;
    int NB2 = (N + 511) / 512;
    int Ecap = E + 15 * N;
    int R = (N + RANGE - 1) / RANGE;
    int Npad2 = R * (RANGE / 2);
    int Ep = (E + PPART - 1) / PPART;

    char* p = (char*)d_ws;
    int*   indeg   = (int*)p;    p += (size_t)N * 4;
    float* nsrc    = (float*)p;  p += (size_t)N * 4;
    float* ndst    = (float*)p;  p += (size_t)N * 4;
    int*   row_ptr = (int*)p;    p += (size_t)(N + 1) * 4;
    int*   bsum    = (int*)p;    p += 1024 * 4;
    float* wt      = (float*)p;  p += (HIDDEN + 1) * 4;
    float* q       = (float*)p;  p += (size_t)(N + 1) * 4;   // + sentinel
    float* nodeval = (float*)p;  p += (size_t)N * 4;
    int*   col     = (int*)p;    p += (size_t)Ecap * 4;
    p = (char*)(((uintptr_t)p + 255) & ~(uintptr_t)255);
    float* embW    = (float*)p;  p += (size_t)V * HIDDEN * 4;
    float* hbuf    = (float*)p;  p += (size_t)N1 * HIDDEN * 4;   // CF8 chunked
    float* tmp     = (float*)p;  p += (size_t)N1 * HIDDEN * 4;   // CF8 chunked

    // packed histogram partials (13.1 MB each) alias dead feature buffers.
    int* inpart  = (int*)tmp;
    int* outpart = (int*)hbuf;

    hipMemsetAsync(out, 0, (size_t)out_size * 4, stream);

    // ---- atomic-free CSR build ----
    hist_kernel<<<R * PPART, 256, 0, stream>>>(src, dst, inpart, outpart, E, Ep, Npad2);
    prefix_kernel<<<NB2, 256, 0, stream>>>(inpart, outpart, indeg, nsrc, ndst, bsum, N, Npad2);
    scan_bsum_kernel<<<1, 1024, 0, stream>>>(bsum, 2 * NB2);
    scan_final_kernel<<<NB, 256, 0, stream>>>(indeg, bsum, row_ptr, col, N);
    fill_kernel<<<R * PPART, 256, 0, stream>>>(src, dst, inpart, row_ptr, col, E, Ep, Npad2);

    // ---- precomputed weights ----
    embw_kernel<<<(V + 3) / 4, 256, 0, stream>>>(emb, Ws + 0 * HIDDEN * HIDDEN, embW, V);
    wtilde_kernel<<<1, 64, 0, stream>>>(Ws + 2 * HIDDEN * HIDDEN, Wreg, bs + 2 * HIDDEN, wt, q, N);

    // ---- features (includes sentinel-row zeroing) ----
    int total = N1 * HIDDEN;
    gather1_kernel<<<(total + 255) / 256, 256, 0, stream>>>(feats, embW, nsrc, tmp, N, N1, total);

    const int GB_SPMM = 1024;
    const int GB_DENSE = 2048;
    int sstride = GB_SPMM * 4;
    int dstride = GB_DENSE * 4;

    // layer 1: hbuf = ((A tmp)*ndst + b0)*nsrc
    spmm_kernel<<<NCHUNK * GB_SPMM, 256, 0, stream>>>(row_ptr, col, tmp, ndst, nsrc,
                                                      bs + 0 * HIDDEN, hbuf, N, N1, sstride);
    // layer 2: tmp = hbuf @ W1 ; hbuf = ((A tmp)*ndst + b1)*nsrc
    dense_kernel<<<GB_DENSE, 256, 0, stream>>>(hbuf, Ws + 1 * HIDDEN * HIDDEN, tmp, N, N1, dstride);
    spmm_kernel<<<NCHUNK * GB_SPMM, 256, 0, stream>>>(row_ptr, col, tmp, ndst, nsrc,
                                                      bs + 1 * HIDDEN, hbuf, N, N1, sstride);
    // collapsed layer 3
    qdot_kernel<<<(N + 31) / 32, 256, 0, stream>>>(hbuf, wt, q, N, N1);
    spmm3_kernel<<<(N + 15) / 16, 256, 0, stream>>>(row_ptr, col, q, ndst, nodeval, N);
    final_kernel<<<NB, 256, 0, stream>>>(gids, nodeval, wt, out, N);
}

// Round 12
// 560.226 us; speedup vs baseline: 1.0294x; 1.0294x over previous
//
#include <hip/hip_runtime.h>

#define HIDDEN 64
#define CF 8         // features per chunk (32 B row = 2 float4)
#define NCHUNK 8     // chunks; chunk = blockIdx&7 -> XCD round-robin, 3.2 MB < 4 MB L2
#define RANGE 8192   // nodes per histogram range
#define RSHIFT 13
#define PPART 64     // edge partitions
#define PSHIFT 6

// ---------- atomic-free degree histograms (packed u16 pairs) ----------
__global__ __launch_bounds__(256) void hist_kernel(const int* __restrict__ src,
                                                   const int* __restrict__ dst,
                                                   int* __restrict__ inpart,
                                                   int* __restrict__ outpart,
                                                   int E, int Ep, int Npad2) {
    __shared__ int hin[RANGE / 2];
    __shared__ int hout[RANGE / 2];
    int r = blockIdx.x >> PSHIFT, p = blockIdx.x & (PPART - 1);
    int base = r << RSHIFT;
    for (int i = threadIdx.x; i < RANGE / 2; i += 256) { hin[i] = 0; hout[i] = 0; }
    __syncthreads();
    int es = p * Ep, ee = min(E, es + Ep);
    for (int e = es + threadIdx.x; e < ee; e += 256) {
        int d = dst[e], s = src[e];
        unsigned dd = (unsigned)(d - base), ss = (unsigned)(s - base);
        if (dd < RANGE) atomicAdd(&hin[dd >> 1], 1 << ((dd & 1) << 4));
        if (ss < RANGE) atomicAdd(&hout[ss >> 1], 1 << ((ss & 1) << 4));
    }
    __syncthreads();
    int* ip = inpart + (size_t)p * Npad2 + (base >> 1);
    int* op = outpart + (size_t)p * Npad2 + (base >> 1);
    for (int i = threadIdx.x; i < RANGE / 2; i += 256) { ip[i] = hin[i]; op[i] = hout[i]; }
}

// ---------- per-node-pair: totals, exclusive prefix over partitions, norms,
// padded-degree block sums ----------
__global__ __launch_bounds__(256) void prefix_kernel(int* __restrict__ inpart,
                                                     const int* __restrict__ outpart,
                                                     int* __restrict__ indeg,
                                                     float* __restrict__ nsrc,
                                                     float* __restrict__ ndst,
                                                     int* __restrict__ bsum,
                                                     int N, int Npad2) {
    int t = threadIdx.x;
    int w = blockIdx.x * 256 + t;     // word index = node pair
    int n0 = w << 1;
    int run0 = 0, run1 = 0, od0 = 0, od1 = 0;
    if (n0 < N) {
#pragma unroll 4
        for (int p = 0; p < PPART; p++) {
            size_t idx = (size_t)p * Npad2 + w;
            int c = inpart[idx];
            int o = outpart[idx];
            inpart[idx] = (run0 & 0xffff) | (run1 << 16);
            run0 += c & 0xffff;  run1 += (c >> 16) & 0xffff;
            od0  += o & 0xffff;  od1  += (o >> 16) & 0xffff;
        }
        indeg[n0] = run0;
        nsrc[n0] = rsqrtf(fmaxf((float)od0, 1.0f));
        ndst[n0] = rsqrtf(fmaxf((float)run0, 1.0f));
        if (n0 + 1 < N) {
            indeg[n0 + 1] = run1;
            nsrc[n0 + 1] = rsqrtf(fmaxf((float)od1, 1.0f));
            ndst[n0 + 1] = rsqrtf(fmaxf((float)run1, 1.0f));
        }
    }
    int v = ((run0 + 15) & ~15) + ((run1 + 15) & ~15);
#pragma unroll
    for (int off = 32; off > 0; off >>= 1) v += __shfl_down(v, off, 64);
    __shared__ int s[4];
    if ((t & 63) == 0) s[t >> 6] = v;
    __syncthreads();
    if (t == 0) {
        bsum[2 * blockIdx.x]     = s[0] + s[1];
        bsum[2 * blockIdx.x + 1] = s[2] + s[3];
    }
}

__global__ void scan_bsum_kernel(int* __restrict__ bsum, int B) {
    __shared__ int tmp[1024];
    int t = threadIdx.x;
    tmp[t] = (t < B) ? bsum[t] : 0;
    __syncthreads();
    for (int off = 1; off < 1024; off <<= 1) {
        int u = (t >= off) ? tmp[t - off] : 0;
        __syncthreads();
        tmp[t] += u;
        __syncthreads();
    }
    if (t < B) bsum[t] = (t > 0) ? tmp[t - 1] : 0;
}

// padded inclusive scan -> row_ptr, fused sentinel pad-fill
__global__ void scan_final_kernel(const int* __restrict__ indeg, const int* __restrict__ bsum,
                                  int* __restrict__ row_ptr, int* __restrict__ col, int N) {
    __shared__ int tmp[256];
    int t = threadIdx.x;
    int n = blockIdx.x * 256 + t;
    int id = (n < N) ? indeg[n] : 0;
    int v = (id + 15) & ~15;
    tmp[t] = (n < N) ? v : 0;
    __syncthreads();
    for (int off = 1; off < 256; off <<= 1) {
        int u = (t >= off) ? tmp[t - off] : 0;
        __syncthreads();
        tmp[t] += u;
        __syncthreads();
    }
    if (n < N) {
        int rp1 = tmp[t] + bsum[blockIdx.x];
        row_ptr[n + 1] = rp1;
        for (int j = rp1 - v + id; j < rp1; j++) col[j] = N;
    }
    if (n == 0) row_ptr[0] = 0;
}

// ---------- atomic-free CSR fill: packed LDS cursors per (range,partition) ----------
__global__ __launch_bounds__(256) void fill_kernel(const int* __restrict__ src,
                                                   const int* __restrict__ dst,
                                                   const int* __restrict__ inpart,
                                                   const int* __restrict__ row_ptr,
                                                   int* __restrict__ col,
                                                   int E, int Ep, int Npad2) {
    __shared__ int lcur[RANGE / 2];
    int r = blockIdx.x >> PSHIFT, p = blockIdx.x & (PPART - 1);
    int base = r << RSHIFT;
    for (int i = threadIdx.x; i < RANGE / 2; i += 256) lcur[i] = 0;
    __syncthreads();
    const int* offs = inpart + (size_t)p * Npad2;
    int es = p * Ep, ee = min(E, es + Ep);
    for (int e = es + threadIdx.x; e < ee; e += 256) {
        int d = dst[e];
        unsigned dd = (unsigned)(d - base);
        if (dd < RANGE) {
            int sh = (dd & 1) << 4;
            int old = atomicAdd(&lcur[dd >> 1], 1 << sh);
            int lrank = (old >> sh) & 0xffff;
            int pbase = (offs[d >> 1] >> ((d & 1) << 4)) & 0xffff;
            col[row_ptr[d] + pbase + lrank] = src[e];
        }
    }
}

// ---------- embW = emb @ W0 ----------
__global__ __launch_bounds__(256) void embw_kernel(const float* __restrict__ emb,
                                                   const float* __restrict__ W,
                                                   float* __restrict__ embW, int V) {
    __shared__ float Wsh[HIDDEN * HIDDEN];
    for (int i = threadIdx.x; i < HIDDEN * HIDDEN; i += blockDim.x) Wsh[i] = W[i];
    __syncthreads();
    int lane = threadIdx.x & 63;
    int v = blockIdx.x * 4 + (threadIdx.x >> 6);
    if (v >= V) return;
    float rv = emb[(size_t)v * HIDDEN + lane];
    float o = 0.0f;
#pragma unroll
    for (int k = 0; k < HIDDEN; k++) o = fmaf(__shfl(rv, k, 64), Wsh[k * HIDDEN + lane], o);
    embW[(size_t)v * HIDDEN + lane] = o;
}

// ---------- w~ = W2 @ Wreg ; wt[64] = b2 . Wreg ; q[N]=0 ; sentinel col segment ----------
__global__ void wtilde_kernel(const float* __restrict__ W2, const float* __restrict__ Wreg,
                              const float* __restrict__ b2, float* __restrict__ wt,
                              float* __restrict__ q, int* __restrict__ col,
                              int sent, int N) {
    int k = threadIdx.x;
    float s = 0.0f;
    for (int j = 0; j < HIDDEN; j++) s += W2[k * HIDDEN + j] * Wreg[j];
    wt[k] = s;
    if (k < 16) col[sent + k] = N;     // all-sentinel segment for branch-free spmm
    float cv = b2[k] * Wreg[k];
#pragma unroll
    for (int off = 32; off > 0; off >>= 1) cv += __shfl_down(cv, off, 64);
    if (k == 0) { wt[HIDDEN] = cv; q[N] = 0.0f; }
}

// ---------- gather1 (+ sentinel row zeroing): over N1 rows ----------
__global__ void gather1_kernel(const int* __restrict__ feats, const float* __restrict__ embW,
                               const float* __restrict__ nsrc, float* __restrict__ hT,
                               int N, int N1, int total) {
    int idx = blockIdx.x * blockDim.x + threadIdx.x;   // c*(N1*8) + n*8 + f
    if (idx >= total) return;
    int c = idx / (N1 * CF);
    int r = idx - c * (N1 * CF);
    int n = r >> 3;
    int f = r & 7;
    hT[idx] = (n < N) ? embW[feats[n] * HIDDEN + c * CF + f] * nsrc[n] : 0.0f;
}

// ---------- dense 64x64 layer, chunked CF8 in/out, 2-node ILP ----------
__global__ __launch_bounds__(256) void dense_kernel(const float* __restrict__ inT,
                                                    const float* __restrict__ W,
                                                    float* __restrict__ outT,
                                                    int N, int N1, int nstride) {
    __shared__ float Wsh[HIDDEN * HIDDEN];
    for (int i = threadIdx.x; i < HIDDEN * HIDDEN; i += blockDim.x) Wsh[i] = W[i];
    __syncthreads();

    int lane = threadIdx.x & 63;
    int warp = threadIdx.x >> 6;
    size_t rowoff = (size_t)(lane >> 3) * N1;
    int f = lane & 7;

    for (int n0 = blockIdx.x * 4 + warp; n0 < N; n0 += 2 * nstride) {
        int n1 = n0 + nstride;
        float rv0 = inT[(rowoff + n0) * CF + f];
        float rv1 = (n1 < N) ? inT[(rowoff + n1) * CF + f] : 0.0f;
        float o0 = 0.0f, o1 = 0.0f;
#pragma unroll
        for (int k = 0; k < HIDDEN; k++) {
            float w = Wsh[k * HIDDEN + lane];
            o0 = fmaf(__shfl(rv0, k, 64), w, o0);
            o1 = fmaf(__shfl(rv1, k, 64), w, o1);
        }
        outT[(rowoff + n0) * CF + f] = o0;
        if (n1 < N) outT[(rowoff + n1) * CF + f] = o1;
    }
}

// ---------- chunked gather-SpMM: CF8 L2-resident, branch-free quad-chain ----------
// lane = nh*32 + e*2 + fq. 4 chains x 2 halves = 8 nodes per wave-iteration.
// Main body: exactly 2 unconditional iterations; chain k's address clamps to
// the all-sentinel segment (zero row, L1-hit) when it >= m[k] -> pure cndmask,
// no branches, 8 col loads + 8 gathers in flight. deg>32 tail (~2%) looped.
__global__ __launch_bounds__(256) void spmm_kernel(const int* __restrict__ row_ptr,
                                                   const int* __restrict__ col,
                                                   const float* __restrict__ tmpT,
                                                   const float* __restrict__ ndst,
                                                   const float* __restrict__ nsrc,
                                                   const float* __restrict__ b,
                                                   float* __restrict__ outT,
                                                   int N, int N1, int nstride, int sent) {
    int lane = threadIdx.x & 63;
    int warp = threadIdx.x >> 6;
    int c = blockIdx.x & 7;
    int nh = lane >> 5;
    int e  = (lane >> 1) & 15;
    int fq = lane & 1;
    const float* __restrict__ chunk = tmpT + (size_t)c * N1 * CF;
    float4 bias = ((const float4*)(b + c * CF))[fq];
    int sentE = sent + e;

    int start = (blockIdx.x >> 3) * 4 + warp;
    for (int n0 = start; n0 < N; n0 += 8 * nstride) {
        int nk[4], j[4], m[4];
        float4 acc[4];
#pragma unroll
        for (int k = 0; k < 4; k++) {
            nk[k] = n0 + (2 * k + nh) * nstride;
            int beg = 0, end = 0;
            if (nk[k] < N) { beg = row_ptr[nk[k]]; end = row_ptr[nk[k] + 1]; }
            j[k] = beg + e;
            m[k] = (end - beg) >> 4;
            acc[k] = make_float4(0.f, 0.f, 0.f, 0.f);
        }
        // main: 2 unconditional, branch-free iterations (covers deg <= 32)
#pragma unroll
        for (int it = 0; it < 2; it++) {
#pragma unroll
            for (int k = 0; k < 4; k++) {
                int jj = (it < m[k]) ? (j[k] + (it << 4)) : sentE;
                int s = col[jj];
                float4 v = *(const float4*)(chunk + (size_t)s * CF + fq * 4);
                acc[k].x += v.x; acc[k].y += v.y; acc[k].z += v.z; acc[k].w += v.w;
            }
        }
        // rare tail: deg > 32
#pragma unroll
        for (int k = 0; k < 4; k++) {
            for (int it = 2; it < m[k]; it++) {
                int s = col[j[k] + (it << 4)];
                float4 v = *(const float4*)(chunk + (size_t)s * CF + fq * 4);
                acc[k].x += v.x; acc[k].y += v.y; acc[k].z += v.z; acc[k].w += v.w;
            }
        }
#pragma unroll
        for (int k = 0; k < 4; k++) {
#pragma unroll
            for (int mm = 2; mm <= 16; mm <<= 1) {
                acc[k].x += __shfl_xor(acc[k].x, mm, 64);
                acc[k].y += __shfl_xor(acc[k].y, mm, 64);
                acc[k].z += __shfl_xor(acc[k].z, mm, 64);
                acc[k].w += __shfl_xor(acc[k].w, mm, 64);
            }
            if (e == 0 && nk[k] < N) {   // lanes 0,1,32,33
                float nd = ndst[nk[k]], ns = nsrc[nk[k]];
                float4 o;
                o.x = (acc[k].x * nd + bias.x) * ns;
                o.y = (acc[k].y * nd + bias.y) * ns;
                o.z = (acc[k].z * nd + bias.z) * ns;
                o.w = (acc[k].w * nd + bias.w) * ns;
                *(float4*)(outT + ((size_t)c * N1 + nk[k]) * CF + fq * 4) = o;
            }
        }
    }
}

// ---------- q[n] = hT[n] . w~ (8 chunks of 8) ----------
__global__ __launch_bounds__(256) void qdot_kernel(const float* __restrict__ hT,
                                                   const float* __restrict__ wt,
                                                   float* __restrict__ q, int N, int N1) {
    int lane = threadIdx.x & 63;
    int warp = threadIdx.x >> 6;
    int ns_ = lane >> 3, f = lane & 7;
    int n = (blockIdx.x * 4 + warp) * 8 + ns_;
    float acc = 0.0f;
#pragma unroll
    for (int c = 0; c < NCHUNK; c++) {
        float v = (n < N) ? hT[((size_t)c * N1 + n) * CF + f] : 0.0f;
        acc += v * wt[c * CF + f];
    }
    acc += __shfl_xor(acc, 1, 64);
    acc += __shfl_xor(acc, 2, 64);
    acc += __shfl_xor(acc, 4, 64);
    if (f == 0 && n < N) q[n] = acc;
}

// ---------- layer-3 scalar gather (padded CSR, 16 lanes/node) ----------
__global__ __launch_bounds__(256) void spmm3_kernel(const int* __restrict__ row_ptr,
                                                    const int* __restrict__ col,
                                                    const float* __restrict__ q,
                                                    const float* __restrict__ ndst,
                                                    float* __restrict__ nodeval, int N) {
    int lane = threadIdx.x & 63;
    int warp = threadIdx.x >> 6;
    int ns_ = lane >> 4, ln = lane & 15;
    int n = blockIdx.x * 16 + warp * 4 + ns_;
    if (n >= N) return;
    int beg = row_ptr[n], end = row_ptr[n + 1];
    float acc = 0.0f;
    for (int j = beg + ln; j < end; j += 16) acc += q[col[j]];
    acc += __shfl_xor(acc, 1, 64);
    acc += __shfl_xor(acc, 2, 64);
    acc += __shfl_xor(acc, 4, 64);
    acc += __shfl_xor(acc, 8, 64);
    if (ln == 0) nodeval[n] = acc * ndst[n];
}

// ---------- final: segmented sum over sorted gids ----------
__global__ __launch_bounds__(256) void final_kernel(const int* __restrict__ gids,
                                                    const float* __restrict__ nodeval,
                                                    const float* __restrict__ wt,
                                                    float* __restrict__ out, int N) {
    int n = blockIdx.x * 256 + threadIdx.x;
    int lane = threadIdx.x & 63;
    float c3 = wt[HIDDEN];
    float v = 0.0f;
    int g = -1;
    if (n < N) { v = nodeval[n] + c3; g = gids[n]; }
#pragma unroll
    for (int off = 1; off < 64; off <<= 1) {
        float u = __shfl_up(v, off, 64);
        int gu = __shfl_up(g, off, 64);
        if (lane >= off && gu == g) v += u;
    }
    int gn = __shfl_down(g, 1, 64);
    bool last = (lane == 63) || (gn != g);
    if (n < N && last) atomicAdd(&out[g], v);
}

extern "C" void kernel_launch(void* const* d_in, const int* in_sizes, int n_in,
                              void* d_out, int out_size, void* d_ws, size_t ws_size,
                              hipStream_t stream) {
    const int*   feats = (const int*)d_in[0];
    const int*   src   = (const int*)d_in[1];
    const int*   dst   = (const int*)d_in[2];
    const int*   gids  = (const int*)d_in[3];
    const float* emb   = (const float*)d_in[5];
    const float* Ws    = (const float*)d_in[6];
    const float* bs    = (const float*)d_in[7];
    const float* Wreg  = (const float*)d_in[8];
    float* out = (float*)d_out;

    int N = in_sizes[0];
    int E = in_sizes[1];
    int V = in_sizes[5] / HIDDEN;
    int N1 = N + 1;                 // +1 sentinel row per chunk
    int NB = (N + 255) / 256;
    int NB2 = (N + 511) / 512;
    int Ecap = E + 15 * N + 16;     // + room for the all-sentinel segment
    int sent = Ecap - 16;
    int R = (N + RANGE - 1) / RANGE;
    int Npad2 = R * (RANGE / 2);
    int Ep = (E + PPART - 1) / PPART;

    char* p = (char*)d_ws;
    int*   indeg   = (int*)p;    p += (size_t)N * 4;
    float* nsrc    = (float*)p;  p += (size_t)N * 4;
    float* ndst    = (float*)p;  p += (size_t)N * 4;
    int*   row_ptr = (int*)p;    p += (size_t)(N + 1) * 4;
    int*   bsum    = (int*)p;    p += 1024 * 4;
    float* wt      = (float*)p;  p += (HIDDEN + 1) * 4;
    float* q       = (float*)p;  p += (size_t)(N + 1) * 4;   // + sentinel
    float* nodeval = (float*)p;  p += (size_t)N * 4;
    int*   col     = (int*)p;    p += (size_t)Ecap * 4;
    p = (char*)(((uintptr_t)p + 255) & ~(uintptr_t)255);
    float* embW    = (float*)p;  p += (size_t)V * HIDDEN * 4;
    float* hbuf    = (float*)p;  p += (size_t)N1 * HIDDEN * 4;   // CF8 chunked
    float* tmp     = (float*)p;  p += (size_t)N1 * HIDDEN * 4;   // CF8 chunked

    // packed histogram partials (13.1 MB each) alias dead feature buffers.
    int* inpart  = (int*)tmp;
    int* outpart = (int*)hbuf;

    hipMemsetAsync(out, 0, (size_t)out_size * 4, stream);

    // ---- atomic-free CSR build ----
    hist_kernel<<<R * PPART, 256, 0, stream>>>(src, dst, inpart, outpart, E, Ep, Npad2);
    prefix_kernel<<<NB2, 256, 0, stream>>>(inpart, outpart, indeg, nsrc, ndst, bsum, N, Npad2);
    scan_bsum_kernel<<<1, 1024, 0, stream>>>(bsum, 2 * NB2);
    scan_final_kernel<<<NB, 256, 0, stream>>>(indeg, bsum, row_ptr, col, N);
    fill_kernel<<<R * PPART, 256, 0, stream>>>(src, dst, inpart, row_ptr, col, E, Ep, Npad2);

    // ---- precomputed weights (+ sentinel col segment) ----
    embw_kernel<<<(V + 3) / 4, 256, 0, stream>>>(emb, Ws + 0 * HIDDEN * HIDDEN, embW, V);
    wtilde_kernel<<<1, 64, 0, stream>>>(Ws + 2 * HIDDEN * HIDDEN, Wreg, bs + 2 * HIDDEN,
                                        wt, q, col, sent, N);

    // ---- features (includes sentinel-row zeroing) ----
    int total = N1 * HIDDEN;
    gather1_kernel<<<(total + 255) / 256, 256, 0, stream>>>(feats, embW, nsrc, tmp, N, N1, total);

    const int GB_SPMM = 1024;
    const int GB_DENSE = 2048;
    int sstride = GB_SPMM * 4;
    int dstride = GB_DENSE * 4;

    // layer 1: hbuf = ((A tmp)*ndst + b0)*nsrc
    spmm_kernel<<<NCHUNK * GB_SPMM, 256, 0, stream>>>(row_ptr, col, tmp, ndst, nsrc,
                                                      bs + 0 * HIDDEN, hbuf, N, N1, sstride, sent);
    // layer 2: tmp = hbuf @ W1 ; hbuf = ((A tmp)*ndst + b1)*nsrc
    dense_kernel<<<GB_DENSE, 256, 0, stream>>>(hbuf, Ws + 1 * HIDDEN * HIDDEN, tmp, N, N1, dstride);
    spmm_kernel<<<NCHUNK * GB_SPMM, 256, 0, stream>>>(row_ptr, col, tmp, ndst, nsrc,
                                                      bs + 1 * HIDDEN, hbuf, N, N1, sstride, sent);
    // collapsed layer 3
    qdot_kernel<<<(N + 31) / 32, 256, 0, stream>>>(hbuf, wt, q, N, N1);
    spmm3_kernel<<<(N + 15) / 16, 256, 0, stream>>>(row_ptr, col, q, ndst, nodeval, N);
    final_kernel<<<NB, 256, 0, stream>>>(gids, nodeval, wt, out, N);
}

// Round 13
// 255.589 us; speedup vs baseline: 2.2563x; 2.1919x over previous
//
#include <hip/hip_runtime.h>

#define HIDDEN 64
#define RANGE 8192   // nodes per histogram range
#define RSHIFT 13
#define PPART 64     // edge partitions
#define PSHIFT 6

// ---------- atomic-free degree histograms (packed u16 pairs) ----------
__global__ __launch_bounds__(256) void hist_kernel(const int* __restrict__ src,
                                                   const int* __restrict__ dst,
                                                   int* __restrict__ inpart,
                                                   int* __restrict__ outpart,
                                                   int E, int Ep, int Npad2) {
    __shared__ int hin[RANGE / 2];
    __shared__ int hout[RANGE / 2];
    int r = blockIdx.x >> PSHIFT, p = blockIdx.x & (PPART - 1);
    int base = r << RSHIFT;
    for (int i = threadIdx.x; i < RANGE / 2; i += 256) { hin[i] = 0; hout[i] = 0; }
    __syncthreads();
    int es = p * Ep, ee = min(E, es + Ep);
    for (int e = es + threadIdx.x; e < ee; e += 256) {
        int d = dst[e], s = src[e];
        unsigned dd = (unsigned)(d - base), ss = (unsigned)(s - base);
        if (dd < RANGE) atomicAdd(&hin[dd >> 1], 1 << ((dd & 1) << 4));
        if (ss < RANGE) atomicAdd(&hout[ss >> 1], 1 << ((ss & 1) << 4));
    }
    __syncthreads();
    int* ip = inpart + (size_t)p * Npad2 + (base >> 1);
    int* op = outpart + (size_t)p * Npad2 + (base >> 1);
    for (int i = threadIdx.x; i < RANGE / 2; i += 256) { ip[i] = hin[i]; op[i] = hout[i]; }
}

// ---------- per-node-pair: totals, exclusive prefix over partitions, norms,
// padded-degree block sums ----------
__global__ __launch_bounds__(256) void prefix_kernel(int* __restrict__ inpart,
                                                     const int* __restrict__ outpart,
                                                     int* __restrict__ indeg,
                                                     float* __restrict__ nsrc,
                                                     float* __restrict__ ndst,
                                                     int* __restrict__ bsum,
                                                     int N, int Npad2) {
    int t = threadIdx.x;
    int w = blockIdx.x * 256 + t;     // word index = node pair
    int n0 = w << 1;
    int run0 = 0, run1 = 0, od0 = 0, od1 = 0;
    if (n0 < N) {
#pragma unroll 4
        for (int p = 0; p < PPART; p++) {
            size_t idx = (size_t)p * Npad2 + w;
            int c = inpart[idx];
            int o = outpart[idx];
            inpart[idx] = (run0 & 0xffff) | (run1 << 16);
            run0 += c & 0xffff;  run1 += (c >> 16) & 0xffff;
            od0  += o & 0xffff;  od1  += (o >> 16) & 0xffff;
        }
        indeg[n0] = run0;
        nsrc[n0] = rsqrtf(fmaxf((float)od0, 1.0f));
        ndst[n0] = rsqrtf(fmaxf((float)run0, 1.0f));
        if (n0 + 1 < N) {
            indeg[n0 + 1] = run1;
            nsrc[n0 + 1] = rsqrtf(fmaxf((float)od1, 1.0f));
            ndst[n0 + 1] = rsqrtf(fmaxf((float)run1, 1.0f));
        }
    }
    int v = ((run0 + 15) & ~15) + ((run1 + 15) & ~15);
#pragma unroll
    for (int off = 32; off > 0; off >>= 1) v += __shfl_down(v, off, 64);
    __shared__ int s[4];
    if ((t & 63) == 0) s[t >> 6] = v;
    __syncthreads();
    if (t == 0) {
        bsum[2 * blockIdx.x]     = s[0] + s[1];
        bsum[2 * blockIdx.x + 1] = s[2] + s[3];
    }
}

__global__ void scan_bsum_kernel(int* __restrict__ bsum, int B) {
    __shared__ int tmp[1024];
    int t = threadIdx.x;
    tmp[t] = (t < B) ? bsum[t] : 0;
    __syncthreads();
    for (int off = 1; off < 1024; off <<= 1) {
        int u = (t >= off) ? tmp[t - off] : 0;
        __syncthreads();
        tmp[t] += u;
        __syncthreads();
    }
    if (t < B) bsum[t] = (t > 0) ? tmp[t - 1] : 0;
}

// padded inclusive scan -> row_ptr, fused sentinel pad-fill
__global__ void scan_final_kernel(const int* __restrict__ indeg, const int* __restrict__ bsum,
                                  int* __restrict__ row_ptr, int* __restrict__ col, int N) {
    __shared__ int tmp[256];
    int t = threadIdx.x;
    int n = blockIdx.x * 256 + t;
    int id = (n < N) ? indeg[n] : 0;
    int v = (id + 15) & ~15;
    tmp[t] = (n < N) ? v : 0;
    __syncthreads();
    for (int off = 1; off < 256; off <<= 1) {
        int u = (t >= off) ? tmp[t - off] : 0;
        __syncthreads();
        tmp[t] += u;
        __syncthreads();
    }
    if (n < N) {
        int rp1 = tmp[t] + bsum[blockIdx.x];
        row_ptr[n + 1] = rp1;
        for (int j = rp1 - v + id; j < rp1; j++) col[j] = N;   // sentinel pads
    }
    if (n == 0) row_ptr[0] = 0;
}

// ---------- atomic-free CSR fill: packed LDS cursors per (range,partition) ----------
__global__ __launch_bounds__(256) void fill_kernel(const int* __restrict__ src,
                                                   const int* __restrict__ dst,
                                                   const int* __restrict__ inpart,
                                                   const int* __restrict__ row_ptr,
                                                   int* __restrict__ col,
                                                   int E, int Ep, int Npad2) {
    __shared__ int lcur[RANGE / 2];
    int r = blockIdx.x >> PSHIFT, p = blockIdx.x & (PPART - 1);
    int base = r << RSHIFT;
    for (int i = threadIdx.x; i < RANGE / 2; i += 256) lcur[i] = 0;
    __syncthreads();
    const int* offs = inpart + (size_t)p * Npad2;
    int es = p * Ep, ee = min(E, es + Ep);
    for (int e = es + threadIdx.x; e < ee; e += 256) {
        int d = dst[e];
        unsigned dd = (unsigned)(d - base);
        if (dd < RANGE) {
            int sh = (dd & 1) << 4;
            int old = atomicAdd(&lcur[dd >> 1], 1 << sh);
            int lrank = (old >> sh) & 0xffff;
            int pbase = (offs[d >> 1] >> ((d & 1) << 4)) & 0xffff;
            col[row_ptr[d] + pbase + lrank] = src[e];
        }
    }
}

// ---------- prep: compose weight chain into u1 + scalars c1,c2,c3 ----------
// u3 = W2@Wreg, u2 = W1@u3, u1 = W0@u2; c3=b2.Wreg, c2=b1.u3, c1=b0.u2.
// wt[0:64]=u1, wt[64]=c1, wt[65]=c2, wt[66]=c3. Also zero y sentinels.
__global__ void prep_kernel(const float* __restrict__ Ws, const float* __restrict__ bs,
                            const float* __restrict__ Wreg, float* __restrict__ wt,
                            float* __restrict__ y0, float* __restrict__ y1,
                            float* __restrict__ y2, int N) {
    __shared__ float u3[HIDDEN], u2[HIDDEN];
    int k = threadIdx.x;   // 64 threads
    const float* W0 = Ws;
    const float* W1 = Ws + HIDDEN * HIDDEN;
    const float* W2 = Ws + 2 * HIDDEN * HIDDEN;
    const float* b0 = bs;
    const float* b1 = bs + HIDDEN;
    const float* b2 = bs + 2 * HIDDEN;
    float s = 0.0f;
    for (int j = 0; j < HIDDEN; j++) s += W2[k * HIDDEN + j] * Wreg[j];
    u3[k] = s;
    __syncthreads();
    s = 0.0f;
    for (int j = 0; j < HIDDEN; j++) s += W1[k * HIDDEN + j] * u3[j];
    u2[k] = s;
    __syncthreads();
    s = 0.0f;
    for (int j = 0; j < HIDDEN; j++) s += W0[k * HIDDEN + j] * u2[j];
    wt[k] = s;   // u1
    float c1v = b0[k] * u2[k], c2v = b1[k] * u3[k], c3v = b2[k] * Wreg[k];
#pragma unroll
    for (int off = 32; off > 0; off >>= 1) {
        c1v += __shfl_down(c1v, off, 64);
        c2v += __shfl_down(c2v, off, 64);
        c3v += __shfl_down(c3v, off, 64);
    }
    if (k == 0) {
        wt[64] = c1v; wt[65] = c2v; wt[66] = c3v;
        y0[N] = 0.0f; y1[N] = 0.0f; y2[N] = 0.0f;
    }
}

// ---------- embu[v] = emb[v] . u1 ----------
__global__ __launch_bounds__(256) void embu_kernel(const float* __restrict__ emb,
                                                   const float* __restrict__ wt,
                                                   float* __restrict__ embu, int V) {
    int lane = threadIdx.x & 63;
    int warp = threadIdx.x >> 6;
    int vs = lane >> 4, ln = lane & 15;
    int v = blockIdx.x * 16 + warp * 4 + vs;
    if (v >= V) return;
    const float* row = emb + (size_t)v * HIDDEN;
    float acc = row[ln] * wt[ln] + row[16 + ln] * wt[16 + ln]
              + row[32 + ln] * wt[32 + ln] + row[48 + ln] * wt[48 + ln];
    acc += __shfl_xor(acc, 1, 64);
    acc += __shfl_xor(acc, 2, 64);
    acc += __shfl_xor(acc, 4, 64);
    acc += __shfl_xor(acc, 8, 64);
    if (ln == 0) embu[v] = acc;
}

// ---------- y0[n] = embu[feats[n]] * nsrc[n] ----------
__global__ void y0_kernel(const int* __restrict__ feats, const float* __restrict__ embu,
                          const float* __restrict__ nsrc, float* __restrict__ y0, int N) {
    int n = blockIdx.x * 256 + threadIdx.x;
    if (n < N) y0[n] = embu[feats[n]] * nsrc[n];
}

// ---------- scalar SpMM: out[n] = (sum_{s in N(n)} y[s]) * ndst[n] + c, opt * nsrc ----------
// padded CSR (pads -> sentinel N, y[N]=0); 16 lanes/node, 4 nodes/wave.
__global__ __launch_bounds__(256) void sspmm_kernel(const int* __restrict__ row_ptr,
                                                    const int* __restrict__ col,
                                                    const float* __restrict__ y,
                                                    const float* __restrict__ ndst,
                                                    const float* __restrict__ nsrc,
                                                    const float* __restrict__ wt, int cidx,
                                                    float* __restrict__ out,
                                                    int N, int scale_out) {
    int lane = threadIdx.x & 63;
    int warp = threadIdx.x >> 6;
    int ns_ = lane >> 4, ln = lane & 15;
    int n = blockIdx.x * 16 + warp * 4 + ns_;
    if (n >= N) return;
    int beg = row_ptr[n], end = row_ptr[n + 1];
    float acc = 0.0f;
    for (int j = beg + ln; j < end; j += 16) acc += y[col[j]];
    acc += __shfl_xor(acc, 1, 64);
    acc += __shfl_xor(acc, 2, 64);
    acc += __shfl_xor(acc, 4, 64);
    acc += __shfl_xor(acc, 8, 64);
    if (ln == 0) {
        float o = acc * ndst[n] + wt[cidx];
        if (scale_out) o *= nsrc[n];
        out[n] = o;
    }
}

// ---------- final: segmented sum of nodeval over sorted gids ----------
__global__ __launch_bounds__(256) void final_kernel(const int* __restrict__ gids,
                                                    const float* __restrict__ nodeval,
                                                    float* __restrict__ out, int N) {
    int n = blockIdx.x * 256 + threadIdx.x;
    int lane = threadIdx.x & 63;
    float v = 0.0f;
    int g = -1;
    if (n < N) { v = nodeval[n]; g = gids[n]; }
#pragma unroll
    for (int off = 1; off < 64; off <<= 1) {
        float u = __shfl_up(v, off, 64);
        int gu = __shfl_up(g, off, 64);
        if (lane >= off && gu == g) v += u;
    }
    int gn = __shfl_down(g, 1, 64);
    bool last = (lane == 63) || (gn != g);
    if (n < N && last) atomicAdd(&out[g], v);
}

extern "C" void kernel_launch(void* const* d_in, const int* in_sizes, int n_in,
                              void* d_out, int out_size, void* d_ws, size_t ws_size,
                              hipStream_t stream) {
    const int*   feats = (const int*)d_in[0];
    const int*   src   = (const int*)d_in[1];
    const int*   dst   = (const int*)d_in[2];
    const int*   gids  = (const int*)d_in[3];
    const float* emb   = (const float*)d_in[5];
    const float* Ws    = (const float*)d_in[6];
    const float* bs    = (const float*)d_in[7];
    const float* Wreg  = (const float*)d_in[8];
    float* out = (float*)d_out;

    int N = in_sizes[0];
    int E = in_sizes[1];
    int V = in_sizes[5] / HIDDEN;
    int NB = (N + 255) / 256;
    int NB2 = (N + 511) / 512;
    int Ecap = E + 15 * N;
    int R = (N + RANGE - 1) / RANGE;
    int Npad2 = R * (RANGE / 2);
    int Ep = (E + PPART - 1) / PPART;

    char* p = (char*)d_ws;
    int*   indeg   = (int*)p;    p += (size_t)N * 4;
    float* nsrc    = (float*)p;  p += (size_t)N * 4;
    float* ndst    = (float*)p;  p += (size_t)N * 4;
    int*   row_ptr = (int*)p;    p += (size_t)(N + 1) * 4;
    int*   bsum    = (int*)p;    p += 1024 * 4;
    float* wt      = (float*)p;  p += 128 * 4;
    float* embu    = (float*)p;  p += (size_t)V * 4;
    float* y0      = (float*)p;  p += (size_t)(N + 1) * 4;   // + sentinel
    float* y1      = (float*)p;  p += (size_t)(N + 1) * 4;
    float* y2      = (float*)p;  p += (size_t)(N + 1) * 4;
    float* nodeval = (float*)p;  p += (size_t)N * 4;
    int*   col     = (int*)p;    p += (size_t)Ecap * 4;
    p = (char*)(((uintptr_t)p + 255) & ~(uintptr_t)255);
    int*   inpart  = (int*)p;    p += (size_t)PPART * Npad2 * 4;
    int*   outpart = (int*)p;    p += (size_t)PPART * Npad2 * 4;

    hipMemsetAsync(out, 0, (size_t)out_size * 4, stream);

    // ---- atomic-free CSR build ----
    hist_kernel<<<R * PPART, 256, 0, stream>>>(src, dst, inpart, outpart, E, Ep, Npad2);
    prefix_kernel<<<NB2, 256, 0, stream>>>(inpart, outpart, indeg, nsrc, ndst, bsum, N, Npad2);
    scan_bsum_kernel<<<1, 1024, 0, stream>>>(bsum, 2 * NB2);
    scan_final_kernel<<<NB, 256, 0, stream>>>(indeg, bsum, row_ptr, col, N);
    fill_kernel<<<R * PPART, 256, 0, stream>>>(src, dst, inpart, row_ptr, col, E, Ep, Npad2);

    // ---- collapsed linear model: weight-chain + scalar node values ----
    prep_kernel<<<1, 64, 0, stream>>>(Ws, bs, Wreg, wt, y0, y1, y2, N);
    embu_kernel<<<(V + 15) / 16, 256, 0, stream>>>(emb, wt, embu, V);
    y0_kernel<<<NB, 256, 0, stream>>>(feats, embu, nsrc, y0, N);

    // 3 scalar SpMMs: y1 = nsrc.(ndst.A y0 + c1); y2 = nsrc.(ndst.A y1 + c2);
    // nodeval = ndst.A y2 + c3
    sspmm_kernel<<<(N + 15) / 16, 256, 0, stream>>>(row_ptr, col, y0, ndst, nsrc, wt, 64,
                                                    y1, N, 1);
    sspmm_kernel<<<(N + 15) / 16, 256, 0, stream>>>(row_ptr, col, y1, ndst, nsrc, wt, 65,
                                                    y2, N, 1);
    sspmm_kernel<<<(N + 15) / 16, 256, 0, stream>>>(row_ptr, col, y2, ndst, nsrc, wt, 66,
                                                    nodeval, N, 0);

    final_kernel<<<NB, 256, 0, stream>>>(gids, nodeval, out, N);
}

// Round 14
// 229.907 us; speedup vs baseline: 2.5083x; 1.1117x over previous
//
#include <hip/hip_runtime.h>

#define HIDDEN 64
#define RANGE 8192   // nodes per histogram range
#define RSHIFT 13
#define PPART 64     // partitions per range (hist/fill)
#define PSHIFT 6
#define RMAX 16      // max ranges supported

// ---------- pass 1: bucket edges by dst-range (pairs) and src-range (srcb) ----------
__global__ __launch_bounds__(256) void bucket_kernel(const int* __restrict__ src,
                                                     const int* __restrict__ dst,
                                                     int2* __restrict__ pairs,
                                                     int* __restrict__ srcb,
                                                     int* __restrict__ gin,
                                                     int* __restrict__ gout,
                                                     int E, int EC, int Cap) {
    __shared__ int cin[RMAX], cout[RMAX], bin_[RMAX], bout_[RMAX];
    int t = threadIdx.x;
    if (t < RMAX) { cin[t] = 0; cout[t] = 0; }
    __syncthreads();
    int es = blockIdx.x * EC, ee = min(E, es + EC);
    for (int e = es + t; e < ee; e += 256) {
        atomicAdd(&cin[dst[e] >> RSHIFT], 1);
        atomicAdd(&cout[src[e] >> RSHIFT], 1);
    }
    __syncthreads();
    if (t < RMAX) {
        bin_[t] = atomicAdd(&gin[t], cin[t]);
        bout_[t] = atomicAdd(&gout[t], cout[t]);
        cin[t] = 0; cout[t] = 0;
    }
    __syncthreads();
    for (int e = es + t; e < ee; e += 256) {
        int s = src[e], d = dst[e];
        int r = d >> RSHIFT;
        int sl = bin_[r] + atomicAdd(&cin[r], 1);
        pairs[(size_t)r * Cap + sl] = make_int2(d, s);
        int r2 = s >> RSHIFT;
        int sl2 = bout_[r2] + atomicAdd(&cout[r2], 1);
        srcb[(size_t)r2 * Cap + sl2] = s;
    }
}

// ---------- pass 2: per-(range,partition) LDS histograms from buckets ----------
// packed u16 pairs: node n -> word n>>1, half n&1.
__global__ __launch_bounds__(256) void hist_kernel(const int2* __restrict__ pairs,
                                                   const int* __restrict__ srcb,
                                                   const int* __restrict__ gin,
                                                   const int* __restrict__ gout,
                                                   int* __restrict__ inpart,
                                                   int* __restrict__ outpart,
                                                   int Cap, int Npad2) {
    __shared__ int hin[RANGE / 2];
    __shared__ int hout[RANGE / 2];
    int r = blockIdx.x >> PSHIFT, p = blockIdx.x & (PPART - 1);
    int base = r << RSHIFT;
    for (int i = threadIdx.x; i < RANGE / 2; i += 256) { hin[i] = 0; hout[i] = 0; }
    __syncthreads();
    int cnt = gin[r];
    int cs = (cnt + PPART - 1) >> PSHIFT;
    int es = p * cs, ee = min(cnt, es + cs);
    const int2* pp = pairs + (size_t)r * Cap;
    for (int e = es + threadIdx.x; e < ee; e += 256) {
        unsigned dd = (unsigned)(pp[e].x - base);
        atomicAdd(&hin[dd >> 1], 1 << ((dd & 1) << 4));
    }
    int cnt2 = gout[r];
    int cs2 = (cnt2 + PPART - 1) >> PSHIFT;
    int es2 = p * cs2, ee2 = min(cnt2, es2 + cs2);
    const int* sp = srcb + (size_t)r * Cap;
    for (int e = es2 + threadIdx.x; e < ee2; e += 256) {
        unsigned ss = (unsigned)(sp[e] - base);
        atomicAdd(&hout[ss >> 1], 1 << ((ss & 1) << 4));
    }
    __syncthreads();
    int* ip = inpart + (size_t)p * Npad2 + (base >> 1);
    int* op = outpart + (size_t)p * Npad2 + (base >> 1);
    for (int i = threadIdx.x; i < RANGE / 2; i += 256) { ip[i] = hin[i]; op[i] = hout[i]; }
}

// ---------- per-node-pair: totals, exclusive prefix over partitions, norms,
// padded-degree block sums ----------
__global__ __launch_bounds__(256) void prefix_kernel(int* __restrict__ inpart,
                                                     const int* __restrict__ outpart,
                                                     int* __restrict__ indeg,
                                                     float* __restrict__ nsrc,
                                                     float* __restrict__ ndst,
                                                     int* __restrict__ bsum,
                                                     int N, int Npad2) {
    int t = threadIdx.x;
    int w = blockIdx.x * 256 + t;     // word index = node pair
    int n0 = w << 1;
    int run0 = 0, run1 = 0, od0 = 0, od1 = 0;
    if (n0 < N) {
#pragma unroll 4
        for (int p = 0; p < PPART; p++) {
            size_t idx = (size_t)p * Npad2 + w;
            int c = inpart[idx];
            int o = outpart[idx];
            inpart[idx] = (run0 & 0xffff) | (run1 << 16);
            run0 += c & 0xffff;  run1 += (c >> 16) & 0xffff;
            od0  += o & 0xffff;  od1  += (o >> 16) & 0xffff;
        }
        indeg[n0] = run0;
        nsrc[n0] = rsqrtf(fmaxf((float)od0, 1.0f));
        ndst[n0] = rsqrtf(fmaxf((float)run0, 1.0f));
        if (n0 + 1 < N) {
            indeg[n0 + 1] = run1;
            nsrc[n0 + 1] = rsqrtf(fmaxf((float)od1, 1.0f));
            ndst[n0 + 1] = rsqrtf(fmaxf((float)run1, 1.0f));
        }
    }
    int v = ((run0 + 15) & ~15) + ((run1 + 15) & ~15);
#pragma unroll
    for (int off = 32; off > 0; off >>= 1) v += __shfl_down(v, off, 64);
    __shared__ int s[4];
    if ((t & 63) == 0) s[t >> 6] = v;
    __syncthreads();
    if (t == 0) {
        bsum[2 * blockIdx.x]     = s[0] + s[1];
        bsum[2 * blockIdx.x + 1] = s[2] + s[3];
    }
}

__global__ void scan_bsum_kernel(int* __restrict__ bsum, int B) {
    __shared__ int tmp[1024];
    int t = threadIdx.x;
    tmp[t] = (t < B) ? bsum[t] : 0;
    __syncthreads();
    for (int off = 1; off < 1024; off <<= 1) {
        int u = (t >= off) ? tmp[t - off] : 0;
        __syncthreads();
        tmp[t] += u;
        __syncthreads();
    }
    if (t < B) bsum[t] = (t > 0) ? tmp[t - 1] : 0;
}

// padded inclusive scan -> row_ptr, fused sentinel pad-fill
__global__ void scan_final_kernel(const int* __restrict__ indeg, const int* __restrict__ bsum,
                                  int* __restrict__ row_ptr, int* __restrict__ col, int N) {
    __shared__ int tmp[256];
    int t = threadIdx.x;
    int n = blockIdx.x * 256 + t;
    int id = (n < N) ? indeg[n] : 0;
    int v = (id + 15) & ~15;
    tmp[t] = (n < N) ? v : 0;
    __syncthreads();
    for (int off = 1; off < 256; off <<= 1) {
        int u = (t >= off) ? tmp[t - off] : 0;
        __syncthreads();
        tmp[t] += u;
        __syncthreads();
    }
    if (n < N) {
        int rp1 = tmp[t] + bsum[blockIdx.x];
        row_ptr[n + 1] = rp1;
        for (int j = rp1 - v + id; j < rp1; j++) col[j] = N;   // sentinel pads
    }
    if (n == 0) row_ptr[0] = 0;
}

// ---------- pass 4: atomic-free CSR fill from dst-buckets ----------
__global__ __launch_bounds__(256) void fill_kernel(const int2* __restrict__ pairs,
                                                   const int* __restrict__ gin,
                                                   const int* __restrict__ inpart,
                                                   const int* __restrict__ row_ptr,
                                                   int* __restrict__ col,
                                                   int Cap, int Npad2) {
    __shared__ int lcur[RANGE / 2];
    int r = blockIdx.x >> PSHIFT, p = blockIdx.x & (PPART - 1);
    int base = r << RSHIFT;
    for (int i = threadIdx.x; i < RANGE / 2; i += 256) lcur[i] = 0;
    __syncthreads();
    const int* offs = inpart + (size_t)p * Npad2;
    int cnt = gin[r];
    int cs = (cnt + PPART - 1) >> PSHIFT;   // must match hist's slicing
    int es = p * cs, ee = min(cnt, es + cs);
    const int2* pp = pairs + (size_t)r * Cap;
    for (int e = es + threadIdx.x; e < ee; e += 256) {
        int2 pr = pp[e];
        int d = pr.x;
        unsigned dd = (unsigned)(d - base);
        int sh = (dd & 1) << 4;
        int old = atomicAdd(&lcur[dd >> 1], 1 << sh);
        int lrank = (old >> sh) & 0xffff;
        int pbase = (offs[d >> 1] >> ((d & 1) << 4)) & 0xffff;
        col[row_ptr[d] + pbase + lrank] = pr.y;
    }
}

// ---------- prep: compose weight chain into u1 + scalars c1,c2,c3 ----------
__global__ void prep_kernel(const float* __restrict__ Ws, const float* __restrict__ bs,
                            const float* __restrict__ Wreg, float* __restrict__ wt,
                            float* __restrict__ y0, float* __restrict__ y1,
                            float* __restrict__ y2, int N) {
    __shared__ float u3[HIDDEN], u2[HIDDEN];
    int k = threadIdx.x;   // 64 threads
    const float* W0 = Ws;
    const float* W1 = Ws + HIDDEN * HIDDEN;
    const float* W2 = Ws + 2 * HIDDEN * HIDDEN;
    const float* b0 = bs;
    const float* b1 = bs + HIDDEN;
    const float* b2 = bs + 2 * HIDDEN;
    float s = 0.0f;
    for (int j = 0; j < HIDDEN; j++) s += W2[k * HIDDEN + j] * Wreg[j];
    u3[k] = s;
    __syncthreads();
    s = 0.0f;
    for (int j = 0; j < HIDDEN; j++) s += W1[k * HIDDEN + j] * u3[j];
    u2[k] = s;
    __syncthreads();
    s = 0.0f;
    for (int j = 0; j < HIDDEN; j++) s += W0[k * HIDDEN + j] * u2[j];
    wt[k] = s;   // u1
    float c1v = b0[k] * u2[k], c2v = b1[k] * u3[k], c3v = b2[k] * Wreg[k];
#pragma unroll
    for (int off = 32; off > 0; off >>= 1) {
        c1v += __shfl_down(c1v, off, 64);
        c2v += __shfl_down(c2v, off, 64);
        c3v += __shfl_down(c3v, off, 64);
    }
    if (k == 0) {
        wt[64] = c1v; wt[65] = c2v; wt[66] = c3v;
        y0[N] = 0.0f; y1[N] = 0.0f; y2[N] = 0.0f;
    }
}

// ---------- embu[v] = emb[v] . u1 ----------
__global__ __launch_bounds__(256) void embu_kernel(const float* __restrict__ emb,
                                                   const float* __restrict__ wt,
                                                   float* __restrict__ embu, int V) {
    int lane = threadIdx.x & 63;
    int warp = threadIdx.x >> 6;
    int vs = lane >> 4, ln = lane & 15;
    int v = blockIdx.x * 16 + warp * 4 + vs;
    if (v >= V) return;
    const float* row = emb + (size_t)v * HIDDEN;
    float acc = row[ln] * wt[ln] + row[16 + ln] * wt[16 + ln]
              + row[32 + ln] * wt[32 + ln] + row[48 + ln] * wt[48 + ln];
    acc += __shfl_xor(acc, 1, 64);
    acc += __shfl_xor(acc, 2, 64);
    acc += __shfl_xor(acc, 4, 64);
    acc += __shfl_xor(acc, 8, 64);
    if (ln == 0) embu[v] = acc;
}

// ---------- y0[n] = embu[feats[n]] * nsrc[n] ----------
__global__ void y0_kernel(const int* __restrict__ feats, const float* __restrict__ embu,
                          const float* __restrict__ nsrc, float* __restrict__ y0, int N) {
    int n = blockIdx.x * 256 + threadIdx.x;
    if (n < N) y0[n] = embu[feats[n]] * nsrc[n];
}

// ---------- scalar SpMM: out[n] = (sum_{s in N(n)} y[s]) * ndst[n] + c, opt * nsrc ----------
__global__ __launch_bounds__(256) void sspmm_kernel(const int* __restrict__ row_ptr,
                                                    const int* __restrict__ col,
                                                    const float* __restrict__ y,
                                                    const float* __restrict__ ndst,
                                                    const float* __restrict__ nsrc,
                                                    const float* __restrict__ wt, int cidx,
                                                    float* __restrict__ out,
                                                    int N, int scale_out) {
    int lane = threadIdx.x & 63;
    int warp = threadIdx.x >> 6;
    int ns_ = lane >> 4, ln = lane & 15;
    int n = blockIdx.x * 16 + warp * 4 + ns_;
    if (n >= N) return;
    int beg = row_ptr[n], end = row_ptr[n + 1];
    float acc = 0.0f;
    for (int j = beg + ln; j < end; j += 16) acc += y[col[j]];
    acc += __shfl_xor(acc, 1, 64);
    acc += __shfl_xor(acc, 2, 64);
    acc += __shfl_xor(acc, 4, 64);
    acc += __shfl_xor(acc, 8, 64);
    if (ln == 0) {
        float o = acc * ndst[n] + wt[cidx];
        if (scale_out) o *= nsrc[n];
        out[n] = o;
    }
}

// ---------- final: segmented sum of nodeval over sorted gids ----------
__global__ __launch_bounds__(256) void final_kernel(const int* __restrict__ gids,
                                                    const float* __restrict__ nodeval,
                                                    float* __restrict__ out, int N) {
    int n = blockIdx.x * 256 + threadIdx.x;
    int lane = threadIdx.x & 63;
    float v = 0.0f;
    int g = -1;
    if (n < N) { v = nodeval[n]; g = gids[n]; }
#pragma unroll
    for (int off = 1; off < 64; off <<= 1) {
        float u = __shfl_up(v, off, 64);
        int gu = __shfl_up(g, off, 64);
        if (lane >= off && gu == g) v += u;
    }
    int gn = __shfl_down(g, 1, 64);
    bool last = (lane == 63) || (gn != g);
    if (n < N && last) atomicAdd(&out[g], v);
}

extern "C" void kernel_launch(void* const* d_in, const int* in_sizes, int n_in,
                              void* d_out, int out_size, void* d_ws, size_t ws_size,
                              hipStream_t stream) {
    const int*   feats = (const int*)d_in[0];
    const int*   src   = (const int*)d_in[1];
    const int*   dst   = (const int*)d_in[2];
    const int*   gids  = (const int*)d_in[3];
    const float* emb   = (const float*)d_in[5];
    const float* Ws    = (const float*)d_in[6];
    const float* bs    = (const float*)d_in[7];
    const float* Wreg  = (const float*)d_in[8];
    float* out = (float*)d_out;

    int N = in_sizes[0];
    int E = in_sizes[1];
    int V = in_sizes[5] / HIDDEN;
    int NB = (N + 255) / 256;
    int NB2 = (N + 511) / 512;
    int Ecap = E + 15 * N;
    int R = (N + RANGE - 1) / RANGE;        // 13 for N=100000 (<= RMAX)
    int Npad2 = R * (RANGE / 2);
    int Cap = E / 8;                        // per-range bucket capacity (mean ~E*RANGE/N)
    const int NBK = 1024;                   // bucket-pass blocks
    int EC = (E + NBK - 1) / NBK;

    char* p = (char*)d_ws;
    int*   indeg   = (int*)p;    p += (size_t)N * 4;
    float* nsrc    = (float*)p;  p += (size_t)N * 4;
    float* ndst    = (float*)p;  p += (size_t)N * 4;
    int*   row_ptr = (int*)p;    p += (size_t)(N + 1) * 4;
    int*   bsum    = (int*)p;    p += 1024 * 4;
    float* wt      = (float*)p;  p += 128 * 4;
    int*   gin     = (int*)p;    p += RMAX * 4;     // zeroed
    int*   gout    = (int*)p;    p += RMAX * 4;     // zeroed
    float* embu    = (float*)p;  p += (size_t)V * 4;
    float* y0      = (float*)p;  p += (size_t)(N + 1) * 4;   // + sentinel
    float* y1      = (float*)p;  p += (size_t)(N + 1) * 4;
    float* y2      = (float*)p;  p += (size_t)(N + 1) * 4;
    float* nodeval = (float*)p;  p += (size_t)N * 4;
    int*   col     = (int*)p;    p += (size_t)Ecap * 4;
    p = (char*)(((uintptr_t)p + 255) & ~(uintptr_t)255);
    int2*  pairs   = (int2*)p;   p += (size_t)R * Cap * 8;
    int*   srcb    = (int*)p;    p += (size_t)R * Cap * 4;
    int*   inpart  = (int*)p;    p += (size_t)PPART * Npad2 * 4;
    int*   outpart = (int*)p;    p += (size_t)PPART * Npad2 * 4;

    hipMemsetAsync(out, 0, (size_t)out_size * 4, stream);
    hipMemsetAsync(gin, 0, RMAX * 8, stream);   // gin + gout

    // ---- bucketed atomic-free CSR build ----
    bucket_kernel<<<NBK, 256, 0, stream>>>(src, dst, pairs, srcb, gin, gout, E, EC, Cap);
    hist_kernel<<<R * PPART, 256, 0, stream>>>(pairs, srcb, gin, gout, inpart, outpart,
                                               Cap, Npad2);
    prefix_kernel<<<NB2, 256, 0, stream>>>(inpart, outpart, indeg, nsrc, ndst, bsum, N, Npad2);
    scan_bsum_kernel<<<1, 1024, 0, stream>>>(bsum, 2 * NB2);
    scan_final_kernel<<<NB, 256, 0, stream>>>(indeg, bsum, row_ptr, col, N);
    fill_kernel<<<R * PPART, 256, 0, stream>>>(pairs, gin, inpart, row_ptr, col, Cap, Npad2);

    // ---- collapsed linear model: weight-chain + scalar node values ----
    prep_kernel<<<1, 64, 0, stream>>>(Ws, bs, Wreg, wt, y0, y1, y2, N);
    embu_kernel<<<(V + 15) / 16, 256, 0, stream>>>(emb, wt, embu, V);
    y0_kernel<<<NB, 256, 0, stream>>>(feats, embu, nsrc, y0, N);

    // 3 scalar SpMMs: y1 = nsrc.(ndst.A y0 + c1); y2 = nsrc.(ndst.A y1 + c2);
    // nodeval = ndst.A y2 + c3
    sspmm_kernel<<<(N + 15) / 16, 256, 0, stream>>>(row_ptr, col, y0, ndst, nsrc, wt, 64,
                                                    y1, N, 1);
    sspmm_kernel<<<(N + 15) / 16, 256, 0, stream>>>(row_ptr, col, y1, ndst, nsrc, wt, 65,
                                                    y2, N, 1);
    sspmm_kernel<<<(N + 15) / 16, 256, 0, stream>>>(row_ptr, col, y2, ndst, nsrc, wt, 66,
                                                    nodeval, N, 0);

    final_kernel<<<NB, 256, 0, stream>>>(gids, nodeval, out, N);
}